// Round 3
// baseline (63.558 us; speedup 1.0000x reference)
//
#include <hip/hip_runtime.h>

#define BB 4
#define CC 256
#define HH 50
#define WW 50
#define KK 1000
#define PP 7
#define NBIN 49           // 7*7
#define SCALE 0.0625f     // 1/16
#define CT 32             // channels per tile
#define NT (CC / CT)      // 8 tiles (== #XCDs)
#define MAXD 17           // max bbox rows/cols (roi <= 16 feat px -> span <= 17)
#define MAXCELL (MAXD * MAXD)

// --- per-axis sample computation, replicating reference boundary handling ---
__device__ __forceinline__ void axis_samples(float start, float bin, int p, float limit,
                                             int idx[4], float w[4]) {
#pragma unroll
    for (int i = 0; i < 2; ++i) {
        float s = (float)(p * 2 + i);
        float c = start + bin * (s + 0.5f) * 0.5f;   // /SR==2 exact as *0.5
        bool valid = (c > -1.0f) && (c < limit);
        c = fmaxf(c, 0.0f);
        float low = floorf(c);
        float high;
        if (low >= limit - 1.0f) { low = limit - 1.0f; c = low; high = low; }
        else high = low + 1.0f;
        float frac = c - low;
        idx[i * 2 + 0] = (int)low;
        idx[i * 2 + 1] = (int)high;
        w[i * 2 + 0] = valid ? (1.0f - frac) : 0.0f;
        w[i * 2 + 1] = valid ? frac : 0.0f;
    }
}

// lowest tap of sample 0 / highest tap of sample 13 (samples are monotone in s)
__device__ __forceinline__ void axis_bounds(float start, float bin, float limit,
                                            int& lo, int& hi) {
    float c0 = fmaxf(start + bin * 0.25f, 0.0f);     // s=0: (0+0.5)/2
    float l0 = floorf(c0);
    if (l0 >= limit - 1.0f) l0 = limit - 1.0f;
    lo = (int)l0;
    float c1 = fmaxf(start + bin * 6.75f, 0.0f);     // s=13: (13+0.5)/2
    float l1 = floorf(c1);
    float h1 = (l1 >= limit - 1.0f) ? (limit - 1.0f) : (l1 + 1.0f);
    hi = (int)h1;
}

// --- one block = (ROI, 32-channel tile). Stage bbox in LDS, gather from LDS. ---
__global__ __launch_bounds__(256) void roialign_kernel(const float* __restrict__ fmap,
                                                       const float* __restrict__ rois,
                                                       float* __restrict__ out) {
    __shared__ float bbox[8 * MAXCELL * 4];      // [q][cell][4ch] : 36992 B, b128-aligned
    __shared__ float sout[CT * NBIN];            // 6272 B, [c][49]
    __shared__ int   s_yo[PP][4], s_xo[PP][4];   // premultiplied cell offsets
    __shared__ float s_yw[PP][4], s_xw[PP][4];

    const int bid  = blockIdx.x;
    const int k    = bid >> 3;                   // ROI
    const int tile = bid & 7;                    // channel tile == XCD slot (L2 locality)
    const int t    = threadIdx.x;

    const int   b  = (int)rois[k * 5 + 0];
    const float x1 = rois[k * 5 + 1] * SCALE;
    const float y1 = rois[k * 5 + 2] * SCALE;
    const float x2 = rois[k * 5 + 3] * SCALE;
    const float y2 = rois[k * 5 + 4] * SCALE;
    const float bw = fmaxf(x2 - x1, 1.0f) * (1.0f / PP);
    const float bh = fmaxf(y2 - y1, 1.0f) * (1.0f / PP);

    int ylo, yhi, xlo, xhi;
    axis_bounds(y1, bh, (float)HH, ylo, yhi);
    axis_bounds(x1, bw, (float)WW, xlo, xhi);
    const int ny = yhi - ylo + 1;
    const int nx = xhi - xlo + 1;

    const float* fbase = fmap + ((size_t)(b * CC + tile * CT)) * (HH * WW);

    if (ny <= MAXD && nx <= MAXD) {
        // ---- sample tables (two waves in parallel) ----
        if (t < PP) {
            int idx[4]; float w[4];
            axis_samples(y1, bh, t, (float)HH, idx, w);
#pragma unroll
            for (int j = 0; j < 4; ++j) { s_yo[t][j] = (idx[j] - ylo) * nx; s_yw[t][j] = w[j]; }
        } else if (t >= 64 && t < 64 + PP) {
            const int p = t - 64;
            int idx[4]; float w[4];
            axis_samples(x1, bw, p, (float)WW, idx, w);
#pragma unroll
            for (int j = 0; j < 4; ++j) { s_xo[p][j] = idx[j] - xlo; s_xw[p][j] = w[j]; }
        }
        // ---- phase 1: stage bbox (NCHW -> LDS [q][cell][4]), channel pairs ----
        const int ncell = ny * nx;
        const int items = 16 * ncell;            // 16 channel-pairs
        for (int i = t; i < items; i += 256) {
            const int x  = i % nx;
            const int t1 = i / nx;
            const int y  = t1 % ny;
            const int c  = (t1 / ny) * 2;        // even channel
            const float* src = fbase + ((size_t)c * HH + (ylo + y)) * WW + (xlo + x);
            const float g0 = src[0];
            const float g1 = src[HH * WW];
            const int cell = y * nx + x;
            const int q    = c >> 2;
            *(float2*)&bbox[(((q * MAXCELL) + cell) << 2) + (c & 3)] = make_float2(g0, g1);
        }
        __syncthreads();
        // ---- phase 2: 49 bins x 4 ch8-groups = 196 threads ----
        if (t < NBIN * 4) {
            const int bin = t >> 2;
            const int ch8 = t & 3;
            const int ph  = bin / 7;
            const int pw  = bin - ph * 7;
            const int q0  = ch8 * 2;
            int yo[4], xo[4]; float wy[4], wx[4];
#pragma unroll
            for (int j = 0; j < 4; ++j) {
                yo[j] = s_yo[ph][j]; wy[j] = s_yw[ph][j];
                xo[j] = s_xo[pw][j]; wx[j] = s_xw[pw][j];
            }
            float acc[8] = {0.f, 0.f, 0.f, 0.f, 0.f, 0.f, 0.f, 0.f};
#pragma unroll
            for (int iy = 0; iy < 4; ++iy) {
#pragma unroll
                for (int ix = 0; ix < 4; ++ix) {
                    const float wgt = wy[iy] * wx[ix];
                    const int cell = yo[iy] + xo[ix];
                    const float4 va = *(const float4*)&bbox[((q0 * MAXCELL + cell) << 2)];
                    const float4 vb = *(const float4*)&bbox[(((q0 + 1) * MAXCELL + cell) << 2)];
                    acc[0] = fmaf(wgt, va.x, acc[0]);
                    acc[1] = fmaf(wgt, va.y, acc[1]);
                    acc[2] = fmaf(wgt, va.z, acc[2]);
                    acc[3] = fmaf(wgt, va.w, acc[3]);
                    acc[4] = fmaf(wgt, vb.x, acc[4]);
                    acc[5] = fmaf(wgt, vb.y, acc[5]);
                    acc[6] = fmaf(wgt, vb.z, acc[6]);
                    acc[7] = fmaf(wgt, vb.w, acc[7]);
                }
            }
            const int c0 = ch8 * 8;
#pragma unroll
            for (int j = 0; j < 8; ++j) sout[(c0 + j) * NBIN + bin] = acc[j] * 0.25f;
        }
    } else {
        // ---- fallback (never hit for benchmark data): direct NCHW gather ----
        if (t < CT) {
            const float* fch = fbase + (size_t)t * (HH * WW);
            for (int ph = 0; ph < PP; ++ph) {
                int ys[4]; float wyf[4];
                axis_samples(y1, bh, ph, (float)HH, ys, wyf);
                for (int pw = 0; pw < PP; ++pw) {
                    int xs[4]; float wxf[4];
                    axis_samples(x1, bw, pw, (float)WW, xs, wxf);
                    float acc = 0.0f;
#pragma unroll
                    for (int i = 0; i < 4; ++i)
#pragma unroll
                        for (int j = 0; j < 4; ++j)
                            acc = fmaf(wyf[i] * wxf[j], fch[ys[i] * WW + xs[j]], acc);
                    sout[t * NBIN + ph * PP + pw] = acc * 0.25f;
                }
            }
        }
    }
    __syncthreads();
    // ---- epilogue: contiguous 6272 B per block, float4 ----
    float4* o4 = (float4*)(out + (size_t)k * (CC * NBIN) + (size_t)tile * (CT * NBIN));
    const float4* s4 = (const float4*)sout;
    for (int i = t; i < CT * NBIN / 4; i += 256) o4[i] = s4[i];
}

extern "C" void kernel_launch(void* const* d_in, const int* in_sizes, int n_in,
                              void* d_out, int out_size, void* d_ws, size_t ws_size,
                              hipStream_t stream) {
    const float* input = (const float*)d_in[0];   // [B,C,H,W] f32
    const float* rois  = (const float*)d_in[1];   // [K,5] f32
    float* out = (float*)d_out;                   // [K,C,7,7] f32
    (void)d_ws; (void)ws_size;

    roialign_kernel<<<KK * NT, 256, 0, stream>>>(input, rois, out);
}

// Round 5
// 43.906 us; speedup vs baseline: 1.4476x; 1.4476x over previous
//
#include <hip/hip_runtime.h>

#define BB 4
#define CC 256
#define HH 50
#define WW 50
#define KK 1000
#define PP 7
#define NBIN 49           // 7*7
#define SCALE 0.0625f     // 1/16
#define CH 128            // channels per gather block
#define ROWQ (WW * CC / 4)   // float4 stride of one y row in NHWC = 3200
#define COLQ (CC / 4)        // float4 stride of one x step = 64

typedef float f32x4 __attribute__((ext_vector_type(4)));

// --- per-axis sample computation, replicating reference boundary handling ---
__device__ __forceinline__ void axis_samples(float start, float bin, int p, float limit,
                                             int idx[4], float w[4]) {
#pragma unroll
    for (int i = 0; i < 2; ++i) {
        float s = (float)(p * 2 + i);
        float c = start + bin * (s + 0.5f) * 0.5f;   // /SR==2 exact as *0.5
        bool valid = (c > -1.0f) && (c < limit);
        c = fmaxf(c, 0.0f);
        float low = floorf(c);
        float high;
        if (low >= limit - 1.0f) { low = limit - 1.0f; c = low; high = low; }
        else high = low + 1.0f;
        float frac = c - low;
        idx[i * 2 + 0] = (int)low;
        idx[i * 2 + 1] = (int)high;
        w[i * 2 + 0] = valid ? (1.0f - frac) : 0.0f;
        w[i * 2 + 1] = valid ? frac : 0.0f;
    }
}

// --- NCHW -> NHWC transpose: block per (b,y), 1024 threads (R2, known-good) ---
__global__ __launch_bounds__(1024) void xpose_kernel(const float* __restrict__ in,
                                                     float* __restrict__ out) {
    __shared__ float tile[CC * 51];           // stride 51 pad
    const int b = blockIdx.x / HH;
    const int y = blockIdx.x % HH;
    const int t = threadIdx.x;
    for (int i = t; i < CC * 25; i += 1024) {
        const int c = i / 25, x2 = i % 25;
        const float2 v = *(const float2*)(in + (((size_t)(b * CC + c) * HH + y) * WW + 2 * x2));
        tile[c * 51 + 2 * x2]     = v.x;
        tile[c * 51 + 2 * x2 + 1] = v.y;
    }
    __syncthreads();
    float* ob = out + ((size_t)(b * HH + y) * WW) * CC;
    for (int j = t; j < WW * (CC / 4); j += 1024) {
        const int x  = j >> 6;
        const int c0 = (j & 63) * 4;
        float4 v = { tile[(c0 + 0) * 51 + x], tile[(c0 + 1) * 51 + x],
                     tile[(c0 + 2) * 51 + x], tile[(c0 + 3) * 51 + x] };
        *(float4*)(ob + (size_t)x * CC + c0) = v;
    }
}

// --- gather: block = (ROI, 128-ch half); half-wave = bin, lane = channel-quad ---
__global__ __launch_bounds__(256) void roialign_kernel(const float4* __restrict__ fmap4,
                                                       const float* __restrict__ rois,
                                                       float* __restrict__ out) {
    __shared__ __align__(16) float sout[CH * NBIN];   // 25088 B, [c][49]
    __shared__ int4   s_yi[PP];  __shared__ float4 s_yw[PP];
    __shared__ int4   s_xi[PP];  __shared__ float4 s_xw[PP];

    const int bid  = blockIdx.x;
    const int k    = bid >> 1;
    const int half = bid & 1;
    const int t    = threadIdx.x;
    const int wave = t >> 6;
    const int lane = t & 63;
    const int hw   = lane >> 5;       // which of the wave's 2 bins
    const int chq  = lane & 31;       // channel-quad within the 128-ch tile

    const int   b  = (int)rois[k * 5 + 0];
    const float x1 = rois[k * 5 + 1] * SCALE;
    const float y1 = rois[k * 5 + 2] * SCALE;
    const float x2 = rois[k * 5 + 3] * SCALE;
    const float y2 = rois[k * 5 + 4] * SCALE;
    const float bw = fmaxf(x2 - x1, 1.0f) * (1.0f / PP);
    const float bh = fmaxf(y2 - y1, 1.0f) * (1.0f / PP);

    if (t < PP) {                                 // y tables (wave 0)
        int idx[4]; float w[4];
        axis_samples(y1, bh, t, (float)HH, idx, w);
        s_yi[t] = make_int4(idx[0] * ROWQ, idx[1] * ROWQ, idx[2] * ROWQ, idx[3] * ROWQ);
        s_yw[t] = make_float4(w[0], w[1], w[2], w[3]);
    } else if (t >= 64 && t < 64 + PP) {          // x tables (wave 1, parallel)
        const int p = t - 64;
        int idx[4]; float w[4];
        axis_samples(x1, bw, p, (float)WW, idx, w);
        s_xi[p] = make_int4(idx[0] * COLQ, idx[1] * COLQ, idx[2] * COLQ, idx[3] * COLQ);
        s_xw[p] = make_float4(w[0], w[1], w[2], w[3]);
    }
    __syncthreads();

    const float4* fbase = fmap4 + (size_t)b * (HH * ROWQ) + half * (CH / 4) + chq;

    for (int bin = wave * 2 + hw; bin < NBIN; bin += 8) {
        const int ph = bin / PP;
        const int pw = bin - ph * PP;
        const int4   yi = s_yi[ph];  const float4 wy = s_yw[ph];
        const int4   xi = s_xi[pw];  const float4 wx = s_xw[pw];
        const int yo[4] = {yi.x, yi.y, yi.z, yi.w};
        const int xo[4] = {xi.x, xi.y, xi.z, xi.w};
        const float wyf[4] = {wy.x, wy.y, wy.z, wy.w};
        const float wxf[4] = {wx.x, wx.y, wx.z, wx.w};
        float4 acc = {0.f, 0.f, 0.f, 0.f};
#pragma unroll
        for (int iy = 0; iy < 4; ++iy) {
#pragma unroll
            for (int ix = 0; ix < 4; ++ix) {
                const float wgt = wyf[iy] * wxf[ix];
                const float4 v = fbase[yo[iy] + xo[ix]];
                acc.x = fmaf(wgt, v.x, acc.x);
                acc.y = fmaf(wgt, v.y, acc.y);
                acc.z = fmaf(wgt, v.z, acc.z);
                acc.w = fmaf(wgt, v.w, acc.w);
            }
        }
        const int c0 = chq * 4;                   // within 128-ch tile
        sout[(c0 + 0) * NBIN + bin] = acc.x * 0.25f;   // stride 49 floats -> bank stride 17, free
        sout[(c0 + 1) * NBIN + bin] = acc.y * 0.25f;
        sout[(c0 + 2) * NBIN + bin] = acc.z * 0.25f;
        sout[(c0 + 3) * NBIN + bin] = acc.w * 0.25f;
    }
    __syncthreads();

    // epilogue: 25088 contiguous bytes per block, nontemporal float4
    f32x4* o4 = (f32x4*)(out + (size_t)k * (CC * NBIN) + (size_t)half * (CH * NBIN));
    const f32x4* s4 = (const f32x4*)sout;
    for (int i = t; i < CH * NBIN / 4; i += 256)
        __builtin_nontemporal_store(s4[i], &o4[i]);
}

// --- fallback: direct NCHW (only if ws too small) ---
__global__ __launch_bounds__(256) void roialign_nchw_kernel(const float* __restrict__ fmap,
                                                            const float* __restrict__ rois,
                                                            float* __restrict__ out) {
    __shared__ __align__(16) float sbuf[CC * NBIN];
    const int k = blockIdx.x;
    const int t = threadIdx.x;
    const int   b  = (int)rois[k * 5 + 0];
    const float x1 = rois[k * 5 + 1] * SCALE;
    const float y1 = rois[k * 5 + 2] * SCALE;
    const float x2 = rois[k * 5 + 3] * SCALE;
    const float y2 = rois[k * 5 + 4] * SCALE;
    const float bw = fmaxf(x2 - x1, 1.0f) * (1.0f / PP);
    const float bh = fmaxf(y2 - y1, 1.0f) * (1.0f / PP);
    for (int ph = 0; ph < PP; ++ph) {
        int ys[4]; float wy[4];
        axis_samples(y1, bh, ph, (float)HH, ys, wy);
        for (int pw = 0; pw < PP; ++pw) {
            int xs[4]; float wx[4];
            axis_samples(x1, bw, pw, (float)WW, xs, wx);
            float acc = 0.0f;
#pragma unroll
            for (int i = 0; i < 4; ++i)
#pragma unroll
                for (int j = 0; j < 4; ++j)
                    acc = fmaf(wy[i] * wx[j],
                               fmap[((size_t)(b * CC + t) * HH + ys[i]) * WW + xs[j]], acc);
            sbuf[t * NBIN + ph * PP + pw] = acc * 0.25f;
        }
    }
    __syncthreads();
    float4* o4 = (float4*)(out + (size_t)k * (CC * NBIN));
    const float4* s4 = (const float4*)sbuf;
    for (int i = t; i < (CC * NBIN) / 4; i += 256) o4[i] = s4[i];
}

extern "C" void kernel_launch(void* const* d_in, const int* in_sizes, int n_in,
                              void* d_out, int out_size, void* d_ws, size_t ws_size,
                              hipStream_t stream) {
    const float* input = (const float*)d_in[0];   // [B,C,H,W] f32
    const float* rois  = (const float*)d_in[1];   // [K,5] f32
    float* out = (float*)d_out;                   // [K,C,7,7] f32

    const size_t need = (size_t)BB * HH * WW * CC * sizeof(float);  // 10.24 MB
    if (ws_size >= need) {
        float* fmap = (float*)d_ws;
        xpose_kernel<<<BB * HH, 1024, 0, stream>>>(input, fmap);
        roialign_kernel<<<KK * 2, 256, 0, stream>>>((const float4*)fmap, rois, out);
    } else {
        roialign_nchw_kernel<<<KK, 256, 0, stream>>>(input, rois, out);
    }
}

// Round 6
// 32.374 us; speedup vs baseline: 1.9633x; 1.3562x over previous
//
#include <hip/hip_runtime.h>

#define BB 4
#define CC 256
#define HH 50
#define WW 50
#define KK 1000
#define PP 7
#define NBIN 49              // 7*7
#define SCALE 0.0625f        // 1/16
#define CH 64                // channels per gather block
#define NQ (CH / 4)          // 16 channel-quads
#define ROWQ (WW * CC / 4)   // float4 stride of one y row in NHWC = 3200
#define COLQ (CC / 4)        // float4 stride of one x step = 64
#define WDS 52               // padded Wd row (rows clamped to [0,49] -> ny <= 50)

typedef float f32x4 __attribute__((ext_vector_type(4)));

// --- per-axis sample computation, replicating reference boundary handling ---
__device__ __forceinline__ void axis_samples(float start, float bin, int p, float limit,
                                             int idx[4], float w[4]) {
#pragma unroll
    for (int i = 0; i < 2; ++i) {
        float s = (float)(p * 2 + i);
        float c = start + bin * (s + 0.5f) * 0.5f;   // /SR==2 exact as *0.5
        bool valid = (c > -1.0f) && (c < limit);
        c = fmaxf(c, 0.0f);
        float low = floorf(c);
        float high;
        if (low >= limit - 1.0f) { low = limit - 1.0f; c = low; high = low; }
        else high = low + 1.0f;
        float frac = c - low;
        idx[i * 2 + 0] = (int)low;
        idx[i * 2 + 1] = (int)high;
        w[i * 2 + 0] = valid ? (1.0f - frac) : 0.0f;
        w[i * 2 + 1] = valid ? frac : 0.0f;
    }
}

// --- NCHW -> NHWC transpose: block per (b,y), 1024 threads (known-good) ---
__global__ __launch_bounds__(1024) void xpose_kernel(const float* __restrict__ in,
                                                     float* __restrict__ out) {
    __shared__ float tile[CC * 51];           // stride 51 pad
    const int b = blockIdx.x / HH;
    const int y = blockIdx.x % HH;
    const int t = threadIdx.x;
    for (int i = t; i < CC * 25; i += 1024) {
        const int c = i / 25, x2 = i % 25;
        const float2 v = *(const float2*)(in + (((size_t)(b * CC + c) * HH + y) * WW + 2 * x2));
        tile[c * 51 + 2 * x2]     = v.x;
        tile[c * 51 + 2 * x2 + 1] = v.y;
    }
    __syncthreads();
    float* ob = out + ((size_t)(b * HH + y) * WW) * CC;
    for (int j = t; j < WW * (CC / 4); j += 1024) {
        const int x  = j >> 6;
        const int c0 = (j & 63) * 4;
        float4 v = { tile[(c0 + 0) * 51 + x], tile[(c0 + 1) * 51 + x],
                     tile[(c0 + 2) * 51 + x], tile[(c0 + 3) * 51 + x] };
        *(float4*)(ob + (size_t)x * CC + c0) = v;
    }
}

// --- separable gather: block = (ROI, 64-ch quarter); thread = (pw, chq) ---
// out[ph][pw] = sum_y Wd[ph][y] * (sum_j wx[pw][j] * F[y][x_j])
__global__ __launch_bounds__(128) void roialign_kernel(const float4* __restrict__ fmap4,
                                                       const float* __restrict__ rois,
                                                       float* __restrict__ out) {
    __shared__ __align__(16) float sout[CH * NBIN];   // 12544 B, [c][49]
    __shared__ float s_wd[PP][WDS];                   // collapsed y-weights (x0.25)
    __shared__ int   s_xo[PP][4];                     // x tap offsets (quad units)
    __shared__ float s_xw[PP][4];

    const int bid     = blockIdx.x;
    const int k       = bid >> 2;        // ROI
    const int quarter = bid & 3;         // channel quarter (L2-locality friendly)
    const int t       = threadIdx.x;

    const int   b  = (int)rois[k * 5 + 0];
    const float x1 = rois[k * 5 + 1] * SCALE;
    const float y1 = rois[k * 5 + 2] * SCALE;
    const float x2 = rois[k * 5 + 3] * SCALE;
    const float y2 = rois[k * 5 + 4] * SCALE;
    const float bw = fmaxf(x2 - x1, 1.0f) * (1.0f / PP);
    const float bh = fmaxf(y2 - y1, 1.0f) * (1.0f / PP);

    // y bbox from the monotone extreme samples (s=0 lowest tap, s=13 highest)
    float c0f = fmaxf(y1 + bh * 0.25f, 0.0f);
    float l0 = floorf(c0f);
    if (l0 >= HH - 1.0f) l0 = HH - 1.0f;
    const int ylo = (int)l0;
    float c1f = fmaxf(y1 + bh * 6.75f, 0.0f);
    float l1 = floorf(c1f);
    float h1 = (l1 >= HH - 1.0f) ? (HH - 1.0f) : (l1 + 1.0f);
    const int ny = (int)h1 - ylo + 1;    // <= 50 always (indices clamped to [0,49])

    for (int i = t; i < PP * WDS; i += 128) (&s_wd[0][0])[i] = 0.0f;
    __syncthreads();

    if (t < PP) {                                 // collapsed y-weight rows
        int idx[4]; float w[4];
        axis_samples(y1, bh, t, (float)HH, idx, w);
#pragma unroll
        for (int j = 0; j < 4; ++j) s_wd[t][idx[j] - ylo] += 0.25f * w[j];
    } else if (t >= 64 && t < 64 + PP) {          // x tables (other wave, parallel)
        const int p = t - 64;
        int idx[4]; float w[4];
        axis_samples(x1, bw, p, (float)WW, idx, w);
#pragma unroll
        for (int j = 0; j < 4; ++j) { s_xo[p][j] = idx[j] * COLQ; s_xw[p][j] = w[j]; }
    }
    __syncthreads();

    const int pw  = t >> 4;          // 0..6 active, 7 idle
    const int chq = t & 15;
    if (pw < PP) {
        const int   xo0 = s_xo[pw][0], xo1 = s_xo[pw][1], xo2 = s_xo[pw][2], xo3 = s_xo[pw][3];
        const float w0 = s_xw[pw][0], w1 = s_xw[pw][1], w2 = s_xw[pw][2], w3 = s_xw[pw][3];
        f32x4 acc[PP] = {};
        const float4* p = fmap4 + (size_t)b * (HH * ROWQ) + (size_t)ylo * ROWQ
                        + quarter * NQ + chq;
        for (int y = 0; y < ny; ++y, p += ROWQ) {
            const float4 v0 = p[xo0], v1 = p[xo1], v2 = p[xo2], v3 = p[xo3];
            float trx = fmaf(w0, v0.x, fmaf(w1, v1.x, fmaf(w2, v2.x, w3 * v3.x)));
            float try_ = fmaf(w0, v0.y, fmaf(w1, v1.y, fmaf(w2, v2.y, w3 * v3.y)));
            float trz = fmaf(w0, v0.z, fmaf(w1, v1.z, fmaf(w2, v2.z, w3 * v3.z)));
            float trw = fmaf(w0, v0.w, fmaf(w1, v1.w, fmaf(w2, v2.w, w3 * v3.w)));
#pragma unroll
            for (int ph = 0; ph < PP; ++ph) {
                const float wy = s_wd[ph][y];          // LDS broadcast
                acc[ph].x = fmaf(wy, trx, acc[ph].x);
                acc[ph].y = fmaf(wy, try_, acc[ph].y);
                acc[ph].z = fmaf(wy, trz, acc[ph].z);
                acc[ph].w = fmaf(wy, trw, acc[ph].w);
            }
        }
        const int c0 = chq * 4;
#pragma unroll
        for (int ph = 0; ph < PP; ++ph) {        // bank = (4chq+pw+...)%32: 2 lanes/bank, free
            const int bin = ph * PP + pw;
            sout[(c0 + 0) * NBIN + bin] = acc[ph].x;
            sout[(c0 + 1) * NBIN + bin] = acc[ph].y;
            sout[(c0 + 2) * NBIN + bin] = acc[ph].z;
            sout[(c0 + 3) * NBIN + bin] = acc[ph].w;
        }
    }
    __syncthreads();

    // epilogue: 12544 contiguous bytes per block, nontemporal float4
    f32x4* o4 = (f32x4*)(out + (size_t)k * (CC * NBIN) + (size_t)quarter * (CH * NBIN));
    const f32x4* s4 = (const f32x4*)sout;
    for (int i = t; i < CH * NBIN / 4; i += 128)
        __builtin_nontemporal_store(s4[i], &o4[i]);
}

// --- fallback: direct NCHW (only if ws too small) ---
__global__ __launch_bounds__(256) void roialign_nchw_kernel(const float* __restrict__ fmap,
                                                            const float* __restrict__ rois,
                                                            float* __restrict__ out) {
    __shared__ __align__(16) float sbuf[CC * NBIN];
    const int k = blockIdx.x;
    const int t = threadIdx.x;
    const int   b  = (int)rois[k * 5 + 0];
    const float x1 = rois[k * 5 + 1] * SCALE;
    const float y1 = rois[k * 5 + 2] * SCALE;
    const float x2 = rois[k * 5 + 3] * SCALE;
    const float y2 = rois[k * 5 + 4] * SCALE;
    const float bw = fmaxf(x2 - x1, 1.0f) * (1.0f / PP);
    const float bh = fmaxf(y2 - y1, 1.0f) * (1.0f / PP);
    for (int ph = 0; ph < PP; ++ph) {
        int ys[4]; float wy[4];
        axis_samples(y1, bh, ph, (float)HH, ys, wy);
        for (int pw = 0; pw < PP; ++pw) {
            int xs[4]; float wx[4];
            axis_samples(x1, bw, pw, (float)WW, xs, wx);
            float acc = 0.0f;
#pragma unroll
            for (int i = 0; i < 4; ++i)
#pragma unroll
                for (int j = 0; j < 4; ++j)
                    acc = fmaf(wy[i] * wx[j],
                               fmap[((size_t)(b * CC + t) * HH + ys[i]) * WW + xs[j]], acc);
            sbuf[t * NBIN + ph * PP + pw] = acc * 0.25f;
        }
    }
    __syncthreads();
    float4* o4 = (float4*)(out + (size_t)k * (CC * NBIN));
    const float4* s4 = (const float4*)sbuf;
    for (int i = t; i < (CC * NBIN) / 4; i += 256) o4[i] = s4[i];
}

extern "C" void kernel_launch(void* const* d_in, const int* in_sizes, int n_in,
                              void* d_out, int out_size, void* d_ws, size_t ws_size,
                              hipStream_t stream) {
    const float* input = (const float*)d_in[0];   // [B,C,H,W] f32
    const float* rois  = (const float*)d_in[1];   // [K,5] f32
    float* out = (float*)d_out;                   // [K,C,7,7] f32

    const size_t need = (size_t)BB * HH * WW * CC * sizeof(float);  // 10.24 MB
    if (ws_size >= need) {
        float* fmap = (float*)d_ws;
        xpose_kernel<<<BB * HH, 1024, 0, stream>>>(input, fmap);
        roialign_kernel<<<KK * 4, 128, 0, stream>>>((const float4*)fmap, rois, out);
    } else {
        roialign_nchw_kernel<<<KK, 256, 0, stream>>>(input, rois, out);
    }
}